// Round 2
// baseline (1285.999 us; speedup 1.0000x reference)
//
#include <hip/hip_runtime.h>

// Problem constants (fixed by the reference).
#define NN   100000      // nodes
#define NE   1600000     // edges
#define NG   1024        // graphs
#define HID  64
#define IN1  80          // layer-1 input feature dim
#define IN2  64          // layer-2 input feature dim

// ------------------------------------------------------------------
// h0[n][f] = concat(shape_emb[x0][0:32], color_emb[x1][0:32], pos_emb[x2][0:16])
// ------------------------------------------------------------------
__global__ __launch_bounds__(256) void k_h0(
    const float* __restrict__ shape_emb, const float* __restrict__ color_emb,
    const float* __restrict__ pos_emb, const int* __restrict__ x,
    float* __restrict__ h0) {
  int idx = blockIdx.x * 256 + threadIdx.x;            // over N*80
  if (idx >= NN * 80) return;
  int n = idx / 80, f = idx - n * 80;
  float v;
  if (f < 32)      v = shape_emb[x[n * 3 + 0] * 32 + f];
  else if (f < 64) v = color_emb[x[n * 3 + 1] * 32 + (f - 32)];
  else             v = pos_emb[x[n * 3 + 2] * 16 + (f - 64)];
  h0[idx] = v;
}

// ------------------------------------------------------------------
// Wcat1 = [root1 (80x64); W1[0]; W1[1]; W1[2]]  (flat concat works: W1 is
// [3][80][64] contiguous).  Same for layer 2.
// ------------------------------------------------------------------
__global__ __launch_bounds__(256) void k_prepw(
    const float* __restrict__ root1, const float* __restrict__ W1,
    const float* __restrict__ root2, const float* __restrict__ W2,
    float* __restrict__ Wc1, float* __restrict__ Wc2) {
  int idx = blockIdx.x * 256 + threadIdx.x;
  const int S1 = 4 * IN1 * 64;    // 20480
  const int S2 = 4 * IN2 * 64;    // 16384
  if (idx < S1) {
    Wc1[idx] = (idx < IN1 * 64) ? root1[idx] : W1[idx - IN1 * 64];
  } else if (idx < S1 + S2) {
    int j = idx - S1;
    Wc2[j] = (j < IN2 * 64) ? root2[j] : W2[j - IN2 * 64];
  }
}

// ------------------------------------------------------------------
// Counting sort of edges by dst: histogram, scan, scatter.
// ------------------------------------------------------------------
__global__ __launch_bounds__(256) void k_hist(const int* __restrict__ dst,
                                              int* __restrict__ deg) {
  int e = blockIdx.x * 256 + threadIdx.x;
  if (e < NE) atomicAdd(&deg[dst[e]], 1);
}

__global__ __launch_bounds__(1024) void k_scan(const int* __restrict__ deg,
                                               int* __restrict__ row_start,
                                               int* __restrict__ cursor) {
  __shared__ int part[1024];
  const int CH = (NN + 1023) / 1024;                    // 98
  int t = threadIdx.x;
  int base = t * CH;
  int s = 0;
  for (int k = 0; k < CH; ++k) {
    int i = base + k;
    if (i < NN) s += deg[i];
  }
  part[t] = s;
  __syncthreads();
  for (int off = 1; off < 1024; off <<= 1) {
    int v = part[t];
    int u = (t >= off) ? part[t - off] : 0;
    __syncthreads();
    part[t] = v + u;
    __syncthreads();
  }
  int run = (t == 0) ? 0 : part[t - 1];                 // exclusive prefix
  for (int k = 0; k < CH; ++k) {
    int i = base + k;
    if (i < NN) {
      row_start[i] = run;
      cursor[i] = run;
      run += deg[i];
    }
  }
  if (t == 1023) row_start[NN] = run;                   // == NE (tail threads
  // past NN contribute 0, so part[1022] == total already)
}

__global__ __launch_bounds__(256) void k_scatter(
    const int* __restrict__ src, const int* __restrict__ dst,
    const int* __restrict__ etype, int* __restrict__ cursor,
    unsigned* __restrict__ elist) {
  int e = blockIdx.x * 256 + threadIdx.x;
  if (e >= NE) return;
  int d = dst[e];
  int p = atomicAdd(&cursor[d], 1);
  elist[p] = (unsigned)src[e] | ((unsigned)etype[e] << 17);   // src < 2^17
}

// ------------------------------------------------------------------
// Fused RGCN layer: per node (one wave, lane = feature):
//   mean-aggregate incoming edges per relation (registers, no atomics),
//   build in-vec [h | m0 | m1 | m2] in LDS, then 8-node register-blocked
//   matvec with Wcat [4*FIN][64] (lane = output feature).
// ------------------------------------------------------------------
template <int FIN>
__global__ __launch_bounds__(256, 4) void k_layer(
    const float* __restrict__ hin, const float* __restrict__ Wcat,
    const float* __restrict__ bias, const int* __restrict__ row_start,
    const unsigned* __restrict__ elist, float* __restrict__ hout) {
  constexpr int INV = 4 * FIN;                     // 320 or 256
  __shared__ float inbuf[4 * 8 * INV];             // 40 KB / 32 KB
  int wave = threadIdx.x >> 6;
  int lane = threadIdx.x & 63;
  int tile = blockIdx.x * 4 + wave;                // 8 nodes per tile
  int nbase = tile * 8;
  if (nbase >= NN) return;
  float* myb = &inbuf[wave * 8 * INV];

  // ---- phase A: gather + aggregate, fill 8 slots ----
  for (int s = 0; s < 8; ++s) {
    int n = nbase + s;
    float* slot = myb + s * INV;
    if (n < NN) {
      const float* hp = hin + (size_t)n * FIN;
      slot[lane] = hp[lane];
      if constexpr (FIN == 80) {
        if (lane < 16) slot[64 + lane] = hp[64 + lane];
      }
      float a0 = 0.f, a1 = 0.f, b0 = 0.f, b1 = 0.f, g0 = 0.f, g1 = 0.f;
      int c0 = 0, c1 = 0, c2 = 0;
      int beg = row_start[n], end = row_start[n + 1];
#pragma unroll 4
      for (int e = beg; e < end; ++e) {
        unsigned w = elist[e];
        int srcn = (int)(w & 0x1FFFFu);
        int r = (int)(w >> 17);
        const float* sp = hin + (size_t)srcn * FIN;
        float f0 = sp[lane];
        float f1 = 0.f;
        if constexpr (FIN == 80) {
          if (lane < 16) f1 = sp[64 + lane];
        }
        if (r == 0)      { a0 += f0; a1 += f1; ++c0; }
        else if (r == 1) { b0 += f0; b1 += f1; ++c1; }
        else             { g0 += f0; g1 += f1; ++c2; }
      }
      float sA = 1.f / (float)max(c0, 1);
      float sB = 1.f / (float)max(c1, 1);
      float sC = 1.f / (float)max(c2, 1);
      slot[FIN + lane]     = a0 * sA;
      slot[2 * FIN + lane] = b0 * sB;
      slot[3 * FIN + lane] = g0 * sC;
      if constexpr (FIN == 80) {
        if (lane < 16) {
          slot[FIN + 64 + lane]     = a1 * sA;
          slot[2 * FIN + 64 + lane] = b1 * sB;
          slot[3 * FIN + 64 + lane] = g1 * sC;
        }
      }
    }
  }
  // Intra-wave LDS RAW: compiler inserts lgkmcnt waits; no barrier needed
  // (each wave reads only its own slots).

  // ---- phase B: matvec, 8 nodes register-blocked, lane = out feature ----
  float bj = bias[lane];
  float acc[8];
#pragma unroll
  for (int s = 0; s < 8; ++s) acc[s] = bj;
  for (int i = 0; i < INV; i += 4) {
    const float* wr = Wcat + (size_t)i * 64 + lane;
    float w0 = wr[0];
    float w1 = wr[64];
    float w2 = wr[128];
    float w3 = wr[192];
#pragma unroll
    for (int s = 0; s < 8; ++s) {
      float4 iv = *reinterpret_cast<const float4*>(myb + s * INV + i);
      acc[s] = fmaf(iv.x, w0, acc[s]);
      acc[s] = fmaf(iv.y, w1, acc[s]);
      acc[s] = fmaf(iv.z, w2, acc[s]);
      acc[s] = fmaf(iv.w, w3, acc[s]);
    }
  }
#pragma unroll
  for (int s = 0; s < 8; ++s) {
    int n = nbase + s;
    if (n < NN) hout[(size_t)n * 64 + lane] = fmaxf(acc[s], 0.f);
  }
}

// ------------------------------------------------------------------
// Pool: batch is sorted, so each wave scans 64 consecutive nodes and emits
// one atomicAdd per (graph-segment, lane).
// ------------------------------------------------------------------
__global__ __launch_bounds__(256) void k_pool(const float* __restrict__ h2,
                                              const int* __restrict__ batch,
                                              float* __restrict__ hg,
                                              int* __restrict__ gcnt) {
  int wave = threadIdx.x >> 6;
  int lane = threadIdx.x & 63;
  int base = (blockIdx.x * 4 + wave) * 64;
  if (base >= NN) return;
  int end = min(base + 64, NN);
  float acc = 0.f;
  int cur = batch[base];
  int cnt = 0;
  for (int n = base; n < end; ++n) {
    int g = batch[n];
    if (g != cur) {
      atomicAdd(&hg[cur * 64 + lane], acc);
      if (lane == 0) atomicAdd(&gcnt[cur], cnt);
      acc = 0.f;
      cnt = 0;
      cur = g;
    }
    acc += h2[(size_t)n * 64 + lane];
    ++cnt;
  }
  atomicAdd(&hg[cur * 64 + lane], acc);
  if (lane == 0) atomicAdd(&gcnt[cur], cnt);
}

// ------------------------------------------------------------------
// Final: out[g] = (hg[g]/max(cnt,1)) @ linW + linb
// ------------------------------------------------------------------
__global__ __launch_bounds__(64) void k_final(const float* __restrict__ hg,
                                              const int* __restrict__ gcnt,
                                              const float* __restrict__ linW,
                                              const float* __restrict__ linb,
                                              float* __restrict__ out) {
  __shared__ float v[64];
  int g = blockIdx.x;
  int lane = threadIdx.x;
  float inv = 1.f / (float)max(gcnt[g], 1);
  v[lane] = hg[g * 64 + lane] * inv;
  __syncthreads();
  if (lane < 10) {
    float o = linb[lane];
#pragma unroll
    for (int j = 0; j < 64; ++j) o = fmaf(v[j], linW[j * 10 + lane], o);
    out[g * 10 + lane] = o;
  }
}

// ------------------------------------------------------------------
extern "C" void kernel_launch(void* const* d_in, const int* in_sizes, int n_in,
                              void* d_out, int out_size, void* d_ws,
                              size_t ws_size, hipStream_t stream) {
  const float* shape_emb = (const float*)d_in[0];
  const float* color_emb = (const float*)d_in[1];
  const float* pos_emb   = (const float*)d_in[2];
  const float* W1    = (const float*)d_in[3];
  const float* root1 = (const float*)d_in[4];
  const float* b1    = (const float*)d_in[5];
  const float* W2    = (const float*)d_in[6];
  const float* root2 = (const float*)d_in[7];
  const float* b2    = (const float*)d_in[8];
  const float* linW  = (const float*)d_in[9];
  const float* linb  = (const float*)d_in[10];
  const int* x     = (const int*)d_in[11];
  const int* eidx  = (const int*)d_in[12];      // [2][E]: src row then dst row
  const int* etype = (const int*)d_in[13];
  const int* batch = (const int*)d_in[14];
  float* out = (float*)d_out;

  // ---- workspace carve (bytes) ----
  char* ws = (char*)d_ws;
  size_t off = 0;
  auto carve = [&](size_t bytes) {
    char* p = ws + off;
    off += (bytes + 255) & ~(size_t)255;
    return p;
  };
  float* h0   = (float*)carve((size_t)NN * 80 * 4);   // 32 MB; reused as h2
  float* h1   = (float*)carve((size_t)NN * 64 * 4);   // 25.6 MB
  float* Wc1  = (float*)carve(4 * IN1 * 64 * 4);
  float* Wc2  = (float*)carve(4 * IN2 * 64 * 4);
  float* hg   = (float*)carve((size_t)NG * 64 * 4);
  int*   gcnt = (int*)carve((size_t)NG * 4);
  int*   deg  = (int*)carve((size_t)NN * 4);
  int*   rs   = (int*)carve((size_t)(NN + 1) * 4);
  int*   curp = (int*)carve((size_t)NN * 4);
  unsigned* elist = (unsigned*)carve((size_t)NE * 4);
  float* h2 = h0;                                     // alias: h0 dead then

  const int* esrc = eidx;
  const int* edst = eidx + NE;

  // ---- zero accumulators (ws is poisoned 0xAA before every call) ----
  hipMemsetAsync(deg, 0, (size_t)NN * 4, stream);
  hipMemsetAsync(hg, 0, (size_t)NG * 64 * 4, stream);
  hipMemsetAsync(gcnt, 0, (size_t)NG * 4, stream);

  // ---- pipeline ----
  k_h0<<<(NN * 80 + 255) / 256, 256, 0, stream>>>(shape_emb, color_emb,
                                                  pos_emb, x, h0);
  k_prepw<<<(4 * IN1 * 64 + 4 * IN2 * 64 + 255) / 256, 256, 0, stream>>>(
      root1, W1, root2, W2, Wc1, Wc2);
  k_hist<<<(NE + 255) / 256, 256, 0, stream>>>(edst, deg);
  k_scan<<<1, 1024, 0, stream>>>(deg, rs, curp);
  k_scatter<<<(NE + 255) / 256, 256, 0, stream>>>(esrc, edst, etype, curp,
                                                  elist);
  {
    int tiles = (NN + 7) / 8;
    int blocks = (tiles + 3) / 4;
    k_layer<IN1><<<blocks, 256, 0, stream>>>(h0, Wc1, b1, rs, elist, h1);
    k_layer<IN2><<<blocks, 256, 0, stream>>>(h1, Wc2, b2, rs, elist, h2);
  }
  k_pool<<<((NN + 63) / 64 + 3) / 4, 256, 0, stream>>>(h2, batch, hg, gcnt);
  k_final<<<NG, 64, 0, stream>>>(hg, gcnt, linW, linb, out);
}

// Round 16
// 939.045 us; speedup vs baseline: 1.3695x; 1.3695x over previous
//
#include <hip/hip_runtime.h>

// Problem constants (fixed by the reference).
#define NN   100000      // nodes
#define NE   1600000     // edges
#define NG   1024        // graphs
#define IN1  80          // layer-1 input feature dim
#define IN2  64          // layer-2 input feature dim

// ------------------------------------------------------------------
// Wc = [W[0]; W[1]; W[2]; root]  ([4][FIN][64] flat; W is [3][FIN][64]
// contiguous).  Both layers in one launch.
// ------------------------------------------------------------------
__global__ __launch_bounds__(256) void k_prepw(
    const float* __restrict__ W1, const float* __restrict__ root1,
    const float* __restrict__ W2, const float* __restrict__ root2,
    float* __restrict__ Wc1, float* __restrict__ Wc2) {
  int idx = blockIdx.x * 256 + threadIdx.x;
  const int S1 = 4 * IN1 * 64;    // 20480
  const int S2 = 4 * IN2 * 64;    // 16384
  if (idx < S1) {
    Wc1[idx] = (idx < 3 * IN1 * 64) ? W1[idx] : root1[idx - 3 * IN1 * 64];
  } else if (idx < S1 + S2) {
    int j = idx - S1;
    Wc2[j] = (j < 3 * IN2 * 64) ? W2[j] : root2[j - 3 * IN2 * 64];
  }
}

// ------------------------------------------------------------------
// Per-(dst,relation) histogram into cinv viewed as int[N][4].
// ------------------------------------------------------------------
__global__ __launch_bounds__(256) void k_hist(const int* __restrict__ dst,
                                              const int* __restrict__ etype,
                                              int* __restrict__ ci) {
  int e = blockIdx.x * 256 + threadIdx.x;
  if (e < NE) atomicAdd(&ci[dst[e] * 4 + etype[e]], 1);
}

// ------------------------------------------------------------------
// In-place scan: cinv int[N][4] counts -> float[N][4]
// {1/max(c0,1), 1/max(c1,1), 1/max(c2,1), int_bits(cursor_start)}.
// Each thread owns its rows; no cross-thread hazard.
// ------------------------------------------------------------------
__global__ __launch_bounds__(1024) void k_scan(float* __restrict__ cinv) {
  __shared__ int part[1024];
  int* ci = (int*)cinv;
  const int CH = (NN + 1023) / 1024;                    // 98
  int t = threadIdx.x;
  int base = t * CH;
  int s = 0;
  for (int k = 0; k < CH; ++k) {
    int i = base + k;
    if (i < NN) {
      int4 c = *reinterpret_cast<const int4*>(&ci[i * 4]);
      s += c.x + c.y + c.z;
    }
  }
  part[t] = s;
  __syncthreads();
  for (int off = 1; off < 1024; off <<= 1) {
    int v = part[t];
    int u = (t >= off) ? part[t - off] : 0;
    __syncthreads();
    part[t] = v + u;
    __syncthreads();
  }
  int run = (t == 0) ? 0 : part[t - 1];                 // exclusive prefix
  for (int k = 0; k < CH; ++k) {
    int i = base + k;
    if (i < NN) {
      int4 c = *reinterpret_cast<const int4*>(&ci[i * 4]);
      float4 iv;
      iv.x = 1.f / (float)max(c.x, 1);
      iv.y = 1.f / (float)max(c.y, 1);
      iv.z = 1.f / (float)max(c.z, 1);
      iv.w = __int_as_float(run);                       // cursor start
      *reinterpret_cast<float4*>(&cinv[i * 4]) = iv;
      run += c.x + c.y + c.z;
    }
  }
}

// ------------------------------------------------------------------
// Scatter edges into dst-sorted list; cursor = int bits of cinv[d][3].
// elist[p] = {src | r<<17, dst}.
// ------------------------------------------------------------------
__global__ __launch_bounds__(256) void k_scatter(
    const int* __restrict__ src, const int* __restrict__ dst,
    const int* __restrict__ etype, float* cinv,
    uint2* __restrict__ elist) {
  int e = blockIdx.x * 256 + threadIdx.x;
  if (e >= NE) return;
  int d = dst[e];
  int p = atomicAdd((int*)cinv + d * 4 + 3, 1);
  elist[p] = make_uint2((unsigned)src[e] | ((unsigned)etype[e] << 17),
                        (unsigned)d);
}

// ------------------------------------------------------------------
// Dense transform, ONE 64-wide output block per launch:
//   out[n] = act(h[n]) @ Wsub (+ bias if ROOT).
// FIRST: build h from embedding tables. RELUIN: relu on read.
// outp row stride = ostride (192 for full-mode t slices, 64 otherwise).
// hin/outp NOT __restrict__: full-mode layer-2 root pass aliases them
// (each row is read into LDS in phase A strictly before phase B writes).
// ------------------------------------------------------------------
template <int FIN, bool RELUIN, bool FIRST, bool ROOT>
__global__ __launch_bounds__(256) void k_transform(
    const float* hin, const float* __restrict__ shape_emb,
    const float* __restrict__ color_emb, const float* __restrict__ pos_emb,
    const int* __restrict__ x, const float* __restrict__ Wsub,
    const float* __restrict__ bias, float* outp, int ostride) {
  constexpr int NPW = 16;
  __shared__ float sl[4][NPW][FIN];
  int wave = threadIdx.x >> 6, lane = threadIdx.x & 63;
  int nbase = (blockIdx.x * 4 + wave) * NPW;
  if (nbase >= NN) return;                 // NN % 16 == 0: no partial waves
  for (int s = 0; s < NPW; ++s) {
    int n = nbase + s;
    float v0, v1 = 0.f;
    if constexpr (FIRST) {
      int x0 = x[n * 3], x1 = x[n * 3 + 1], x2 = x[n * 3 + 2];
      v0 = (lane < 32) ? shape_emb[x0 * 32 + lane]
                       : color_emb[x1 * 32 + lane - 32];
      if (lane < 16) v1 = pos_emb[x2 * 16 + lane];
    } else {
      const float* hp = hin + (size_t)n * FIN;
      v0 = hp[lane];
      if constexpr (RELUIN) v0 = fmaxf(v0, 0.f);
      if constexpr (FIN == 80) {
        if (lane < 16) {
          v1 = hp[64 + lane];
          if constexpr (RELUIN) v1 = fmaxf(v1, 0.f);
        }
      }
    }
    sl[wave][s][lane] = v0;
    if constexpr (FIN == 80) {
      if (lane < 16) sl[wave][s][64 + lane] = v1;
    }
  }
  // Intra-wave LDS RAW only; compiler inserts lgkmcnt waits.
  float binit = 0.f;
  if constexpr (ROOT) binit = bias[lane];
  float acc[NPW];
#pragma unroll
  for (int s = 0; s < NPW; ++s) acc[s] = binit;
  const float* wp = Wsub + lane;
  for (int i = 0; i < FIN; i += 4) {
    float w0 = wp[i * 64];
    float w1 = wp[i * 64 + 64];
    float w2 = wp[i * 64 + 128];
    float w3 = wp[i * 64 + 192];
#pragma unroll
    for (int s = 0; s < NPW; ++s) {
      float4 iv = *reinterpret_cast<const float4*>(&sl[wave][s][i]);
      acc[s] = fmaf(iv.x, w0, acc[s]);
      acc[s] = fmaf(iv.y, w1, acc[s]);
      acc[s] = fmaf(iv.z, w2, acc[s]);
      acc[s] = fmaf(iv.w, w3, acc[s]);
    }
  }
#pragma unroll
  for (int s = 0; s < NPW; ++s)
    outp[(size_t)(nbase + s) * ostride + lane] = acc[s];
}

// ------------------------------------------------------------------
// Edge-parallel aggregation over dst-sorted elist. One wave = 128-edge
// chunk, lane = feature. For edges with relation in rmask:
//   acc += t[src*tstride + r*rmul + lane] * cinv[dst*4 + r]
// flushed per dst-run with one coalesced atomicAdd into o[dst].
// full mode: tstride=192, rmul=64, rmask=7 (one pass)
// lite mode: tstride=64,  rmul=0,  rmask=1<<r (three passes)
// ------------------------------------------------------------------
__global__ __launch_bounds__(256) void k_agg(
    const uint2* __restrict__ elist, const float* __restrict__ t,
    const float* __restrict__ cinv, float* __restrict__ o,
    int tstride, int rmul, unsigned rmask) {
  constexpr int CHK = 128;
  int wave_id = blockIdx.x * 4 + (threadIdx.x >> 6);
  int lane = threadIdx.x & 63;
  int beg = wave_id * CHK;
  if (beg >= NE) return;
  int end = min(beg + CHK, NE);
  float acc = 0.f;
  int cur = -1;
  bool any = false;
  for (int i0 = beg; i0 < end; i0 += 8) {
    int m = min(8, end - i0);
    uint2 eb[8];
    float vb[8], wb[8];
#pragma unroll
    for (int k = 0; k < 8; ++k)
      if (k < m) eb[k] = elist[i0 + k];
#pragma unroll
    for (int k = 0; k < 8; ++k) {
      vb[k] = 0.f;
      wb[k] = 0.f;
      if (k < m) {
        int r = (int)(eb[k].x >> 17);
        if ((rmask >> r) & 1u) {
          int s = (int)(eb[k].x & 0x1FFFFu);
          vb[k] = t[(size_t)s * tstride + r * rmul + lane];
          wb[k] = cinv[eb[k].y * 4 + r];
        }
      }
    }
#pragma unroll
    for (int k = 0; k < 8; ++k)
      if (k < m) {
        int d = (int)eb[k].y;
        if (d != cur) {
          if (cur >= 0 && any) atomicAdd(&o[(size_t)cur * 64 + lane], acc);
          acc = 0.f;
          any = false;
          cur = d;
        }
        int r = (int)(eb[k].x >> 17);
        if ((rmask >> r) & 1u) {
          acc = fmaf(vb[k], wb[k], acc);
          any = true;
        }
      }
  }
  if (cur >= 0 && any) atomicAdd(&o[(size_t)cur * 64 + lane], acc);
}

// ------------------------------------------------------------------
// Pool: batch sorted; wave scans 64 consecutive nodes (relu on read),
// one atomicAdd per (segment, lane).
// ------------------------------------------------------------------
__global__ __launch_bounds__(256) void k_pool(const float* __restrict__ o2,
                                              const int* __restrict__ batch,
                                              float* __restrict__ hg,
                                              int* __restrict__ gcnt) {
  int wave = threadIdx.x >> 6;
  int lane = threadIdx.x & 63;
  int base = (blockIdx.x * 4 + wave) * 64;
  if (base >= NN) return;
  int end = min(base + 64, NN);
  float acc = 0.f;
  int cur = batch[base];
  int cnt = 0;
  for (int n = base; n < end; ++n) {
    int g = batch[n];
    if (g != cur) {
      atomicAdd(&hg[cur * 64 + lane], acc);
      if (lane == 0) atomicAdd(&gcnt[cur], cnt);
      acc = 0.f;
      cnt = 0;
      cur = g;
    }
    acc += fmaxf(o2[(size_t)n * 64 + lane], 0.f);
    ++cnt;
  }
  atomicAdd(&hg[cur * 64 + lane], acc);
  if (lane == 0) atomicAdd(&gcnt[cur], cnt);
}

// ------------------------------------------------------------------
// Final: out[g] = (hg[g]/max(cnt,1)) @ linW + linb
// ------------------------------------------------------------------
__global__ __launch_bounds__(64) void k_final(const float* __restrict__ hg,
                                              const int* __restrict__ gcnt,
                                              const float* __restrict__ linW,
                                              const float* __restrict__ linb,
                                              float* __restrict__ out) {
  __shared__ float v[64];
  int g = blockIdx.x;
  int lane = threadIdx.x;
  float inv = 1.f / (float)max(gcnt[g], 1);
  v[lane] = hg[g * 64 + lane] * inv;
  __syncthreads();
  if (lane < 10) {
    float o = linb[lane];
#pragma unroll
    for (int j = 0; j < 64; ++j) o = fmaf(v[j], linW[j * 10 + lane], o);
    out[g * 10 + lane] = o;
  }
}

// ------------------------------------------------------------------
extern "C" void kernel_launch(void* const* d_in, const int* in_sizes, int n_in,
                              void* d_out, int out_size, void* d_ws,
                              size_t ws_size, hipStream_t stream) {
  const float* shape_emb = (const float*)d_in[0];
  const float* color_emb = (const float*)d_in[1];
  const float* pos_emb   = (const float*)d_in[2];
  const float* W1    = (const float*)d_in[3];
  const float* root1 = (const float*)d_in[4];
  const float* b1    = (const float*)d_in[5];
  const float* W2    = (const float*)d_in[6];
  const float* root2 = (const float*)d_in[7];
  const float* b2    = (const float*)d_in[8];
  const float* linW  = (const float*)d_in[9];
  const float* linb  = (const float*)d_in[10];
  const int* x     = (const int*)d_in[11];
  const int* eidx  = (const int*)d_in[12];      // [2][E]: src row then dst row
  const int* etype = (const int*)d_in[13];
  const int* batch = (const int*)d_in[14];
  float* out = (float*)d_out;

  // ---- workspace carve (bytes, 256-aligned) ----
  char* ws = (char*)d_ws;
  size_t off = 0;
  auto carve = [&](size_t bytes) {
    char* p = ws + off;
    off += (bytes + 255) & ~(size_t)255;
    return p;
  };
  // common: 40.4 MB
  float* o1   = (float*)carve((size_t)NN * 64 * 4);    // 25.6 MB
  uint2* elist = (uint2*)carve((size_t)NE * 8);        // 12.8 MB
  float* Wc1  = (float*)carve(4 * IN1 * 64 * 4);
  float* Wc2  = (float*)carve(4 * IN2 * 64 * 4);
  float* cinv = (float*)carve((size_t)NN * 4 * 4);     // counts->inv + cursor
  float* hg   = (float*)carve((size_t)NG * 64 * 4);
  int*   gcnt = (int*)carve((size_t)NG * 4);

  // mode select (ws_size is constant across calls -> capture-stable):
  // full needs common + 76.8 MB (t[N][192]); lite needs common + 51.2 MB.
  bool full_mode = (ws_size >= off + (size_t)NN * 192 * 4 + 4096);
  float *t, *o2;
  if (full_mode) {
    t  = (float*)carve((size_t)NN * 192 * 4);          // all 3 relations
    o2 = o1;   // safe alias: layer-2 root transform reads each o1 row
               // (phase A, LDS) strictly before writing it (phase B).
  } else {
    t  = (float*)carve((size_t)NN * 64 * 4);           // one relation slice
    o2 = (float*)carve((size_t)NN * 64 * 4);           // separate output
  }

  const int* esrc = eidx;
  const int* edst = eidx + NE;

  // ---- zero accumulators (ws is poisoned 0xAA before every call) ----
  hipMemsetAsync(cinv, 0, (size_t)NN * 4 * 4, stream);
  hipMemsetAsync(hg, 0, (size_t)NG * 64 * 4, stream);
  hipMemsetAsync(gcnt, 0, (size_t)NG * 4, stream);

  // ---- build sorted edge structure ----
  k_prepw<<<(4 * IN1 * 64 + 4 * IN2 * 64 + 255) / 256, 256, 0, stream>>>(
      W1, root1, W2, root2, Wc1, Wc2);
  k_hist<<<(NE + 255) / 256, 256, 0, stream>>>(edst, etype, (int*)cinv);
  k_scan<<<1, 1024, 0, stream>>>(cinv);
  k_scatter<<<(NE + 255) / 256, 256, 0, stream>>>(esrc, edst, etype, cinv,
                                                  elist);

  int tb = ((NN / 16) + 3) / 4;                        // 1563 blocks
  int ab = ((NE / 128) + 3) / 4;                       // 3125 blocks

  if (full_mode) {
    // layer 1: three t slices + root -> o1, one agg pass
    for (int r = 0; r < 3; ++r)
      k_transform<IN1, false, true, false><<<tb, 256, 0, stream>>>(
          nullptr, shape_emb, color_emb, pos_emb, x, Wc1 + r * IN1 * 64,
          nullptr, t + r * 64, 192);
    k_transform<IN1, false, true, true><<<tb, 256, 0, stream>>>(
        nullptr, shape_emb, color_emb, pos_emb, x, Wc1 + 3 * IN1 * 64, b1,
        o1, 64);
    k_agg<<<ab, 256, 0, stream>>>(elist, t, cinv, o1, 192, 64, 7u);
    // layer 2: r slices first (o1 intact), root LAST (alias-safe), agg
    for (int r = 0; r < 3; ++r)
      k_transform<IN2, true, false, false><<<tb, 256, 0, stream>>>(
          o1, nullptr, nullptr, nullptr, nullptr, Wc2 + r * IN2 * 64,
          nullptr, t + r * 64, 192);
    k_transform<IN2, true, false, true><<<tb, 256, 0, stream>>>(
        o1, nullptr, nullptr, nullptr, nullptr, Wc2 + 3 * IN2 * 64, b2,
        o2, 64);
    k_agg<<<ab, 256, 0, stream>>>(elist, t, cinv, o2, 192, 64, 7u);
  } else {
    // layer 1: root first (writes o1), then per-relation {transform, agg}
    k_transform<IN1, false, true, true><<<tb, 256, 0, stream>>>(
        nullptr, shape_emb, color_emb, pos_emb, x, Wc1 + 3 * IN1 * 64, b1,
        o1, 64);
    for (int r = 0; r < 3; ++r) {
      k_transform<IN1, false, true, false><<<tb, 256, 0, stream>>>(
          nullptr, shape_emb, color_emb, pos_emb, x, Wc1 + r * IN1 * 64,
          nullptr, t, 64);
      k_agg<<<ab, 256, 0, stream>>>(elist, t, cinv, o1, 64, 0, 1u << r);
    }
    // layer 2: o2 separate; root first (reads o1), then per-relation
    k_transform<IN2, true, false, true><<<tb, 256, 0, stream>>>(
        o1, nullptr, nullptr, nullptr, nullptr, Wc2 + 3 * IN2 * 64, b2,
        o2, 64);
    for (int r = 0; r < 3; ++r) {
      k_transform<IN2, true, false, false><<<tb, 256, 0, stream>>>(
          o1, nullptr, nullptr, nullptr, nullptr, Wc2 + r * IN2 * 64,
          nullptr, t, 64);
      k_agg<<<ab, 256, 0, stream>>>(elist, t, cinv, o2, 64, 0, 1u << r);
    }
  }

  // ---- pool (relu on read) + classifier ----
  k_pool<<<((NN + 63) / 64 + 3) / 4, 256, 0, stream>>>(o2, batch, hg, gcnt);
  k_final<<<NG, 64, 0, stream>>>(hg, gcnt, linW, linb, out);
}